// Round 1
// baseline (160.133 us; speedup 1.0000x reference)
//
#include <hip/hip_runtime.h>
#include <hip/hip_bf16.h>
#include <math.h>

#define DIM 1024
#define HEADS 16
#define HEAD_DIM 64
#define MAXSEQ 4096
#define BATCH 16
#define CHUNK 1024
#define NCHUNK (MAXSEQ / CHUNK)

// ---------------- Kernel A: QKV projection ----------------
// out[mat][b][i] = sum_j token[b][j] * W_mat[i][j]
// grid (64, 3), block 256. Each wave computes 4 output rows i for all 16 b.
__global__ __launch_bounds__(256) void qkv_proj(
    const float* __restrict__ token,
    const float* __restrict__ Wq, const float* __restrict__ Wk,
    const float* __restrict__ Wv,
    float* __restrict__ out /* 3 x 16 x 1024 */) {
  __shared__ float tok[BATCH * DIM];  // 64 KiB
  for (int idx = threadIdx.x; idx < BATCH * DIM; idx += 256)
    tok[idx] = token[idx];
  __syncthreads();

  const float* W = (blockIdx.y == 0) ? Wq : ((blockIdx.y == 1) ? Wk : Wv);
  float* o = out + (size_t)blockIdx.y * BATCH * DIM;

  const int wave = threadIdx.x >> 6;
  const int lane = threadIdx.x & 63;
  const int i0 = blockIdx.x * 16 + wave * 4;

  float acc[4][16];
#pragma unroll
  for (int ii = 0; ii < 4; ++ii)
#pragma unroll
    for (int b = 0; b < 16; ++b) acc[ii][b] = 0.f;

  for (int t = 0; t < 16; ++t) {
    const int j = t * 64 + lane;
    float tk[16];
#pragma unroll
    for (int b = 0; b < 16; ++b) tk[b] = tok[b * DIM + j];
#pragma unroll
    for (int ii = 0; ii < 4; ++ii) {
      const float w = W[(size_t)(i0 + ii) * DIM + j];
#pragma unroll
      for (int b = 0; b < 16; ++b) acc[ii][b] = fmaf(w, tk[b], acc[ii][b]);
    }
  }

#pragma unroll
  for (int ii = 0; ii < 4; ++ii)
#pragma unroll
    for (int b = 0; b < 16; ++b) {
      float v = acc[ii][b];
#pragma unroll
      for (int m = 32; m >= 1; m >>= 1) v += __shfl_xor(v, m);
      if (lane == 0) o[(size_t)b * DIM + i0 + ii] = v;
    }
}

// ---------------- Kernel B: flash-decode attention partials ----------------
// grid (NCHUNK, HEADS, BATCH), block 256 (4 waves).
// partial layout per (b,h,c): [m, l, acc[64]]  (66 floats)
__global__ __launch_bounds__(256) void attn_partial(
    const float* __restrict__ kc, const float* __restrict__ vc,
    const float* __restrict__ qkv, const int* __restrict__ pos_p,
    float* __restrict__ part) {
  const int c = blockIdx.x, h = blockIdx.y, b = blockIdx.z;
  const int tid = threadIdx.x;
  const int wave = tid >> 6, lane = tid & 63;
  const int quarter = lane >> 4, lq = lane & 15;
  const int pos = pos_p[0];
  const int nk = pos + 1;
  const int s0 = c * CHUNK;

  const float* q = qkv + (size_t)b * DIM + h * HEAD_DIM;
  const float* knew = qkv + 1 * BATCH * DIM + (size_t)b * DIM + h * HEAD_DIM;
  const float* vnew = qkv + 2 * BATCH * DIM + (size_t)b * DIM + h * HEAD_DIM;
  const float* kbase = kc + (size_t)b * MAXSEQ * DIM + h * HEAD_DIM;
  const float* vbase = vc + (size_t)b * MAXSEQ * DIM + h * HEAD_DIM;

  const float scale = 0.125f;  // 1/sqrt(64)
  float4 q4 = *(const float4*)(q + lq * 4);
  q4.x *= scale; q4.y *= scale; q4.z *= scale; q4.w *= scale;

  __shared__ float sc[CHUNK];
  __shared__ float wred[4];
  __shared__ __align__(16) float vout[4][64];

  // ---- phase 1: scores ----
#pragma unroll 4
  for (int it = 0; it < 64; ++it) {
    const int sl = wave * 256 + it * 4 + quarter;
    const int s = s0 + sl;
    const bool valid = (s < nk);
    float d = 0.f;
    if (valid) {
      const float* krow = (s == pos) ? knew : (kbase + (size_t)s * DIM);
      const float4 k4 = *(const float4*)(krow + lq * 4);
      d = q4.x * k4.x + q4.y * k4.y + q4.z * k4.z + q4.w * k4.w;
    }
    d += __shfl_xor(d, 1);
    d += __shfl_xor(d, 2);
    d += __shfl_xor(d, 4);
    d += __shfl_xor(d, 8);
    if (lq == 0) sc[sl] = valid ? d : -INFINITY;
  }
  __syncthreads();

  // ---- phase 2: softmax (max + exp + sum) ----
  float lm = -INFINITY;
#pragma unroll
  for (int r = 0; r < 4; ++r) lm = fmaxf(lm, sc[tid + r * 256]);
#pragma unroll
  for (int m = 32; m >= 1; m >>= 1) lm = fmaxf(lm, __shfl_xor(lm, m));
  if (lane == 0) wred[wave] = lm;
  __syncthreads();
  const float m = fmaxf(fmaxf(wred[0], wred[1]), fmaxf(wred[2], wred[3]));
  __syncthreads();  // everyone read wred before reuse

  float lsum = 0.f;
#pragma unroll
  for (int r = 0; r < 4; ++r) {
    const int idx = tid + r * 256;
    const float s = sc[idx];
    const float p = (s == -INFINITY) ? 0.f : __expf(s - m);
    lsum += p;
    sc[idx] = p;  // own slot only
  }
#pragma unroll
  for (int mm = 32; mm >= 1; mm >>= 1) lsum += __shfl_xor(lsum, mm);
  __syncthreads();  // sc[] p-values visible; wred free to reuse
  if (lane == 0) wred[wave] = lsum;
  __syncthreads();
  const float ltot = wred[0] + wred[1] + wred[2] + wred[3];

  // ---- phase 3: V accumulate ----
  float4 a4 = make_float4(0.f, 0.f, 0.f, 0.f);
#pragma unroll 4
  for (int it = 0; it < 64; ++it) {
    const int sl = wave * 256 + it * 4 + quarter;
    const int s = s0 + sl;
    if (s < nk) {
      const float* vrow = (s == pos) ? vnew : (vbase + (size_t)s * DIM);
      const float4 v4 = *(const float4*)(vrow + lq * 4);
      const float p = sc[sl];
      a4.x = fmaf(p, v4.x, a4.x);
      a4.y = fmaf(p, v4.y, a4.y);
      a4.z = fmaf(p, v4.z, a4.z);
      a4.w = fmaf(p, v4.w, a4.w);
    }
  }
  // reduce across quarters (lanes with same lq): xor 16, 32
  a4.x += __shfl_xor(a4.x, 16); a4.x += __shfl_xor(a4.x, 32);
  a4.y += __shfl_xor(a4.y, 16); a4.y += __shfl_xor(a4.y, 32);
  a4.z += __shfl_xor(a4.z, 16); a4.z += __shfl_xor(a4.z, 32);
  a4.w += __shfl_xor(a4.w, 16); a4.w += __shfl_xor(a4.w, 32);
  if (quarter == 0) *(float4*)(&vout[wave][lq * 4]) = a4;
  __syncthreads();

  const size_t base = (((size_t)(b * HEADS + h)) * NCHUNK + c) * 66;
  if (tid < 64) {
    const float a = vout[0][tid] + vout[1][tid] + vout[2][tid] + vout[3][tid];
    part[base + 2 + tid] = a;
  }
  if (tid == 0) { part[base] = m; part[base + 1] = ltot; }
}

// ---------------- Kernel C: combine partials ----------------
__global__ __launch_bounds__(64) void attn_combine(
    const float* __restrict__ part, float* __restrict__ attn) {
  const int bh = blockIdx.x;
  const int b = bh >> 4, h = bh & 15;
  const int d = threadIdx.x;
  const float* p0 = part + (size_t)bh * NCHUNK * 66;
  float M = -INFINITY;
#pragma unroll
  for (int c = 0; c < NCHUNK; ++c) M = fmaxf(M, p0[c * 66]);
  float L = 0.f, o = 0.f;
#pragma unroll
  for (int c = 0; c < NCHUNK; ++c) {
    const float mc = p0[c * 66];
    if (mc > -INFINITY) {
      const float w = __expf(mc - M);
      L += p0[c * 66 + 1] * w;
      o = fmaf(p0[c * 66 + 2 + d], w, o);
    }
  }
  attn[(size_t)b * DIM + h * HEAD_DIM + d] = o / L;
}

// ---------------- Kernel D: output projection ----------------
__global__ __launch_bounds__(256) void o_proj(
    const float* __restrict__ attn, const float* __restrict__ Wo,
    float* __restrict__ out) {
  __shared__ float tok[BATCH * DIM];
  for (int idx = threadIdx.x; idx < BATCH * DIM; idx += 256)
    tok[idx] = attn[idx];
  __syncthreads();

  const int wave = threadIdx.x >> 6;
  const int lane = threadIdx.x & 63;
  const int i0 = blockIdx.x * 16 + wave * 4;

  float acc[4][16];
#pragma unroll
  for (int ii = 0; ii < 4; ++ii)
#pragma unroll
    for (int b = 0; b < 16; ++b) acc[ii][b] = 0.f;

  for (int t = 0; t < 16; ++t) {
    const int j = t * 64 + lane;
    float tk[16];
#pragma unroll
    for (int b = 0; b < 16; ++b) tk[b] = tok[b * DIM + j];
#pragma unroll
    for (int ii = 0; ii < 4; ++ii) {
      const float w = Wo[(size_t)(i0 + ii) * DIM + j];
#pragma unroll
      for (int b = 0; b < 16; ++b) acc[ii][b] = fmaf(w, tk[b], acc[ii][b]);
    }
  }

#pragma unroll
  for (int ii = 0; ii < 4; ++ii)
#pragma unroll
    for (int b = 0; b < 16; ++b) {
      float v = acc[ii][b];
#pragma unroll
      for (int m = 32; m >= 1; m >>= 1) v += __shfl_xor(v, m);
      if (lane == 0) out[(size_t)b * DIM + i0 + ii] = v;
    }
}

extern "C" void kernel_launch(void* const* d_in, const int* in_sizes, int n_in,
                              void* d_out, int out_size, void* d_ws, size_t ws_size,
                              hipStream_t stream) {
  const float* token = (const float*)d_in[0];
  const float* kc = (const float*)d_in[1];
  const float* vc = (const float*)d_in[2];
  const float* Wq = (const float*)d_in[3];
  const float* Wk = (const float*)d_in[4];
  const float* Wv = (const float*)d_in[5];
  const float* Wv_ = (const float*)d_in[5];
  const float* Wo = (const float*)d_in[6];
  const int* pos = (const int*)d_in[7];
  float* out = (float*)d_out;
  float* ws = (float*)d_ws;

  // workspace layout (floats):
  //  [0, 49152)          : q,k,v projections (3 x 16 x 1024)
  //  [49152, 116736)     : attention partials 16*16*4*66
  //  [116736, 133120)    : combined attention output 16 x 1024
  float* qkv = ws;
  float* part = ws + 3 * BATCH * DIM;
  float* attn = part + (size_t)BATCH * HEADS * NCHUNK * 66;

  hipLaunchKernelGGL(qkv_proj, dim3(64, 3), dim3(256), 0, stream,
                     token, Wq, Wk, Wv, qkv);
  hipLaunchKernelGGL(attn_partial, dim3(NCHUNK, HEADS, BATCH), dim3(256), 0,
                     stream, kc, vc, qkv, pos, part);
  hipLaunchKernelGGL(attn_combine, dim3(BATCH * HEADS), dim3(64), 0, stream,
                     part, attn);
  hipLaunchKernelGGL(o_proj, dim3(64), dim3(256), 0, stream, attn, Wo, out);
  (void)Wv_; (void)in_sizes; (void)n_in; (void)out_size; (void)ws_size;
}